// Round 2
// baseline (388.931 us; speedup 1.0000x reference)
//
#include <hip/hip_runtime.h>
#include <hip/hip_bf16.h>

// SelfAttention non-local block: B=8, C=512, N=4096, CQK=32.  All-MFMA bf16 path.
// v5 (pass2 only; resubmission — round-1 bench failed on container acquisition):
//  - produce/consume interleave: the 8 produce tiles of chunk+1 are distributed
//    1-per-nt-group inside the two consume loops. v4 ran produce (VALU/exp-heavy,
//    MFMA-light) and consume (MFMA-heavy, VALU-idle) as separate phases; with only
//    2 waves/SIMD (256 regs/wave) the idle pipe in each phase was never filled --
//    measured per-CU chunk time ~= SUM of pipe times (7240 cyc) vs max pipe 2800.
//    Interleaving feeds the MFMA pipe continuously within one wave and hides
//    exp2/pack VALU + QK-MFMA latency under consume MFMAs. Register-neutral.
//  - last-chunk produce guard dropped (uses in-register aqp, writes a never-read
//    LDS buffer; keeps hot body branch-free). loadQ/loadV guards kept (OOB).
// ws: vb 33.5MB | xT 33.5MB | qb 2MB | kb 2MB | Wvb 512KB | Wqb 32KB | Wkb 32KB | Lneg 128KB

typedef __attribute__((ext_vector_type(8))) short s16x8;
typedef __attribute__((ext_vector_type(4))) float f32x4;

#define MFMA16(a, b, c) __builtin_amdgcn_mfma_f32_16x16x32_bf16((a), (b), (c), 0, 0, 0)

__device__ __forceinline__ ushort f2bf(float f) {
  union { float f; unsigned u; } v; v.f = f;
  return (ushort)((v.u + 0x8000u) >> 16);
}
__device__ __forceinline__ unsigned pack_bf16(float lo, float hi) {  // (hi<<16)|lo
  union { float f; unsigned u; } a, b; a.f = lo; b.f = hi;
  return __builtin_amdgcn_perm(b.u + 0x8000u, a.u + 0x8000u, 0x07060302u);
}

// ---------------- kernel 1: weights -> bf16 (Wq pre-scaled by log2e) ----------------
__global__ void k_cvt_w(const float* __restrict__ Wq, const float* __restrict__ Wk,
                        const float* __restrict__ Wv, ushort* __restrict__ Wqb,
                        ushort* __restrict__ Wkb, ushort* __restrict__ Wvb) {
  int i = blockIdx.x * 256 + threadIdx.x;
  if (i < 262144) Wvb[i] = f2bf(Wv[i]);
  else if (i < 278528) Wqb[i - 262144] = f2bf(Wq[i - 262144] * 1.4426950408889634f);
  else if (i < 294912) Wkb[i - 278528] = f2bf(Wk[i - 278528]);
}

// ---------------- kernel 2: transpose x -> xT bf16 ----------------
// Tile 64c x 256n. Phase1: float4 row loads (1KB contiguous per row), pack n-pairs,
// SoA LDS U[2][64][65] (even/odd pair split => <=2-way banks). Phase2: 8-lane groups
// build 128B-contiguous xT rows via v_perm extraction.
__global__ __launch_bounds__(256) void k_xpose(const float* __restrict__ x,
                                               ushort* __restrict__ xT) {
  const int b = blockIdx.z, c0 = blockIdx.y * 64, n0 = blockIdx.x * 256;
  __shared__ uint U[2][64][65];
  const int t = threadIdx.x;
  const int wv = t >> 6, ln = t & 63;
  const float* xp = x + ((size_t)b * 512 + c0 + wv * 16) * 4096 + n0 + ln * 4;
#pragma unroll
  for (int i = 0; i < 16; ++i) {
    float4 f = *(const float4*)(xp + (size_t)i * 4096);
    U[0][wv * 16 + i][ln] = pack_bf16(f.x, f.y);   // pairs (4ln,4ln+1)   -> pair idx 2ln
    U[1][wv * 16 + i][ln] = pack_bf16(f.z, f.w);   // pairs (4ln+2,4ln+3) -> pair idx 2ln+1
  }
  __syncthreads();
  const int c_seg = (t & 7) * 8;
#pragma unroll
  for (int pass = 0; pass < 8; ++pass) {
    const int nl = pass * 32 + (t >> 3);
    const int p = nl >> 1;              // pair index
    const int h = p & 1, idx = p >> 1;  // SoA half, slot
    const uint sel = (nl & 1) ? 0x07060302u : 0x05040100u;
    uint o[4];
#pragma unroll
    for (int j = 0; j < 4; ++j) {
      uint ua = U[h][c_seg + 2 * j][idx];
      uint ub = U[h][c_seg + 2 * j + 1][idx];
      o[j] = __builtin_amdgcn_perm(ub, ua, sel);   // (bf(c_odd)<<16)|bf(c_even)
    }
    *(uint4*)(xT + ((size_t)b * 4096 + n0 + nl) * 512 + c0 + c_seg) = *(uint4*)o;
  }
}

// ---------------- kernel 3: fused q/k/v projection from xT ----------------
__global__ __launch_bounds__(256, 2) void k_proj(const ushort* __restrict__ xT,
                                                 const ushort* __restrict__ Wqb,
                                                 const ushort* __restrict__ Wkb,
                                                 const ushort* __restrict__ Wvb,
                                                 ushort* __restrict__ qb,
                                                 ushort* __restrict__ kb,
                                                 ushort* __restrict__ vb) {
  const int b = blockIdx.y, n0 = blockIdx.x * 64;
  const int lane = threadIdx.x & 63, w = threadIdx.x >> 6;
  const int quad = lane >> 4, l15 = lane & 15;
  const ushort* xT_b = xT + (size_t)b * 4096 * 512;

  const ushort* Wqk = (w < 2) ? (Wqb + (size_t)(w * 16 + l15) * 512)
                              : (Wkb + (size_t)((w - 2) * 16 + l15) * 512);

  f32x4 accv[8][4], accqk[4];
#pragma unroll
  for (int i = 0; i < 8; ++i)
#pragma unroll
    for (int nt = 0; nt < 4; ++nt) accv[i][nt] = {0.f, 0.f, 0.f, 0.f};
#pragma unroll
  for (int nt = 0; nt < 4; ++nt) accqk[nt] = {0.f, 0.f, 0.f, 0.f};

  for (int k0 = 0; k0 < 512; k0 += 32) {
    s16x8 bx[4];
#pragma unroll
    for (int nt = 0; nt < 4; ++nt)
      bx[nt] = *(const s16x8*)(xT_b + (size_t)(n0 + nt * 16 + l15) * 512 + k0 + quad * 8);
#pragma unroll
    for (int i = 0; i < 8; ++i) {
      s16x8 av = *(const s16x8*)(Wvb + (size_t)((8 * w + i) * 16 + l15) * 512 + k0 + quad * 8);
#pragma unroll
      for (int nt = 0; nt < 4; ++nt) accv[i][nt] = MFMA16(av, bx[nt], accv[i][nt]);
    }
    s16x8 aqk = *(const s16x8*)(Wqk + k0 + quad * 8);
#pragma unroll
    for (int nt = 0; nt < 4; ++nt) accqk[nt] = MFMA16(aqk, bx[nt], accqk[nt]);
  }

  ushort* vb_b = vb + (size_t)b * 512 * 4096;
#pragma unroll
  for (int i = 0; i < 8; ++i)
#pragma unroll
    for (int nt = 0; nt < 4; ++nt)
#pragma unroll
      for (int r = 0; r < 4; ++r)
        vb_b[(size_t)((8 * w + i) * 16 + quad * 4 + r) * 4096 + n0 + nt * 16 + l15] =
            f2bf(accv[i][nt][r]);

  ushort* qk_out = (w < 2) ? (qb + (size_t)b * 4096 * 32) : (kb + (size_t)b * 4096 * 32);
#pragma unroll
  for (int nt = 0; nt < 4; ++nt) {
    ushort4 u;
    u.x = f2bf(accqk[nt][0]); u.y = f2bf(accqk[nt][1]);
    u.z = f2bf(accqk[nt][2]); u.w = f2bf(accqk[nt][3]);
    *(ushort4*)(qk_out + (size_t)(n0 + nt * 16 + l15) * 32 + (w & 1) * 16 + quad * 4) = u;
  }
}

// ---------------- kernel 4: pass1 — Lneg[b][m] = -log2(sum_n 2^(S'[m,n])) ----------------
__global__ __launch_bounds__(256) void k_pass1(const ushort* __restrict__ qb,
                                               const ushort* __restrict__ kb,
                                               float* __restrict__ Lneg) {
  const int b = blockIdx.y, mt = blockIdx.x;
  const int lane = threadIdx.x & 63, w = threadIdx.x >> 6;
  const int quad = lane >> 4, l15 = lane & 15;
  const int m = mt * 64 + w * 16;
  const ushort* qb_b = qb + (size_t)b * 4096 * 32;
  const ushort* kb_b = kb + (size_t)b * 4096 * 32;
  const s16x8 aqf = *(const s16x8*)(qb_b + (size_t)(m + l15) * 32 + quad * 8);
  float ps[4] = {0.f, 0.f, 0.f, 0.f};
  const f32x4 zf = {0.f, 0.f, 0.f, 0.f};
  for (int n0 = 0; n0 < 4096; n0 += 64) {
#pragma unroll
    for (int nt = 0; nt < 4; ++nt) {
      s16x8 bk = *(const s16x8*)(kb_b + (size_t)(n0 + nt * 16 + l15) * 32 + quad * 8);
      f32x4 s = MFMA16(aqf, bk, zf);
#pragma unroll
      for (int r = 0; r < 4; ++r) ps[r] += exp2f(s[r]);
    }
  }
  for (int off = 1; off < 16; off <<= 1)
#pragma unroll
    for (int r = 0; r < 4; ++r) ps[r] += __shfl_xor(ps[r], off, 64);
  if (l15 == 0)
#pragma unroll
    for (int r = 0; r < 4; ++r)
      Lneg[(size_t)b * 4096 + m + quad * 4 + r] = -log2f(ps[r]);
}

// ---------------- kernel 5: pass2 — out = V @ 2^(S' + Lneg) ----------------
// Grid 512 = 8 b (XCD) x 32 ntb x 2 cb. Block 4 waves: tile 256c x 128n, chunk 64 m.
// v5: per chunk, the 8 produce tiles (for chunk+1, other LDS buffer) are interleaved
// 1-per-nt-group into the consume MFMA stream, so exp2/pack VALU and the QK MFMA
// latency hide under PV MFMAs within a single wave (we only have 2 waves/SIMD).
__global__ __launch_bounds__(256, 2) void k_pass2(const ushort* __restrict__ qb,
                                                  const ushort* __restrict__ kb,
                                                  const ushort* __restrict__ vb,
                                                  const float* __restrict__ Lneg,
                                                  float* __restrict__ out) {
  const int blk = blockIdx.x;
  const int b = blk & 7, blkb = blk >> 3;
  const int ntb = blkb & 31, cb = blkb >> 5;
  const int nbase = ntb * 128;
  const int lane = threadIdx.x & 63, w = threadIdx.x >> 6;
  const int quad = lane >> 4, l15 = lane & 15;
  const int wm = w & 1, wn = w >> 1;
  const int cbase = cb * 256 + w * 64;
  const int swz = l15 & 7;

  __shared__ __align__(16) ushort PT[2][128 * 64];  // [n row: 128B], 16B-granule XOR swizzle

  const ushort* qb_b = qb + (size_t)b * 4096 * 32;
  const ushort* kb_b = kb + (size_t)b * 4096 * 32;
  const ushort* vb_b = vb + (size_t)b * 512 * 4096;
  const float* L_b = Lneg + (size_t)b * 4096;

  s16x8 kf[4];
#pragma unroll
  for (int i = 0; i < 4; ++i)
    kf[i] = *(const s16x8*)(kb_b + (size_t)(nbase + (4 * wn + i) * 16 + l15) * 32 + quad * 8);

  f32x4 acc[4][8];
#pragma unroll
  for (int ci = 0; ci < 4; ++ci)
#pragma unroll
    for (int nt = 0; nt < 8; ++nt) acc[ci][nt] = {0.f, 0.f, 0.f, 0.f};

  s16x8 aqp[2];    // prefetched q A-frags for next produce (2 m-tiles)
  float4 l4p[2];   // prefetched Lneg
  s16x8 va[4][2];  // prefetched v A-frags for current chunk

  auto loadQ = [&](int chunk) {
    const int m0 = chunk * 64;
#pragma unroll
    for (int j = 0; j < 2; ++j) {
      const int M = 2 * wm + j;
      aqp[j] = *(const s16x8*)(qb_b + (size_t)(m0 + M * 16 + l15) * 32 + quad * 8);
      l4p[j] = *(const float4*)(L_b + m0 + M * 16 + quad * 4);
    }
  };
  auto loadV = [&](int chunk) {
    const int m0 = chunk * 64;
#pragma unroll
    for (int ci = 0; ci < 4; ++ci) {
      const ushort* vrow = vb_b + (size_t)(cbase + ci * 16 + l15) * 4096 + m0;
      va[ci][0] = *(const s16x8*)(vrow + quad * 8);
      va[ci][1] = *(const s16x8*)(vrow + 32 + quad * 8);
    }
  };
  // one produce tile: QK MFMA (with Lneg as C-in) -> exp2 -> pack -> ds_write.
  // j in {0,1} selects the wave's m-tile, i in {0..3} the wave's n-tile.
  auto produce_tile = [&](int buf, int j, int i) {
    char* Pw = (char*)&PT[buf][0];
    const int M = 2 * wm + j;
    const int T = 4 * wn + i;
    f32x4 cin; cin.x = l4p[j].x; cin.y = l4p[j].y; cin.z = l4p[j].z; cin.w = l4p[j].w;
    f32x4 s = MFMA16(aqp[j], kf[i], cin);             // S' + Lneg
    uint2 u;
    u.x = pack_bf16(exp2f(s.x), exp2f(s.y));
    u.y = pack_bf16(exp2f(s.z), exp2f(s.w));
    const int row = T * 16 + l15;
    const int gran = (2 * M + (quad >> 1)) ^ swz;
    *(uint2*)(Pw + row * 128 + gran * 16 + (quad & 1) * 8) = u;
  };

  loadQ(0);
#pragma unroll
  for (int j = 0; j < 2; ++j)
#pragma unroll
    for (int i = 0; i < 4; ++i) produce_tile(0, j, i);   // prologue: produce chunk 0
  loadQ(1);
  loadV(0);

  for (int chunk = 0; chunk < 64; ++chunk) {
    const int buf = chunk & 1;
    __syncthreads();
    const char* P = (const char*)&PT[buf][0];
    // --- first-half P reads (issued before any ds_write of this iteration) ---
    s16x8 p0[4], p1[4];
#pragma unroll
    for (int nt = 0; nt < 4; ++nt) {
      const int row = nt * 16 + l15;
      p0[nt] = *(const s16x8*)(P + row * 128 + (quad ^ swz) * 16);
      p1[nt] = *(const s16x8*)(P + row * 128 + ((4 + quad) ^ swz) * 16);
    }
    // --- consume first half, interleaved with produce tiles j=0 (into buf^1) ---
    // (chunk 63's produce reuses aqp(63) in-register and writes a never-read
    //  buffer: numerically and memory-safe, keeps the hot body branch-free.)
#pragma unroll
    for (int nt = 0; nt < 4; ++nt) {
#pragma unroll
      for (int ci = 0; ci < 4; ++ci) {
        acc[ci][nt] = MFMA16(va[ci][0], p0[nt], acc[ci][nt]);
        acc[ci][nt] = MFMA16(va[ci][1], p1[nt], acc[ci][nt]);
      }
      produce_tile(buf ^ 1, 0, nt);
    }
    // --- second-half P reads ---
    s16x8 r0[4], r1[4];
#pragma unroll
    for (int nt = 0; nt < 4; ++nt) {
      const int row = (nt + 4) * 16 + l15;
      r0[nt] = *(const s16x8*)(P + row * 128 + (quad ^ swz) * 16);
      r1[nt] = *(const s16x8*)(P + row * 128 + ((4 + quad) ^ swz) * 16);
    }
    // --- consume second half, interleaved with produce tiles j=1 ---
#pragma unroll
    for (int nt = 0; nt < 4; ++nt) {
#pragma unroll
      for (int ci = 0; ci < 4; ++ci) {
        acc[ci][nt + 4] = MFMA16(va[ci][0], r0[nt], acc[ci][nt + 4]);
        acc[ci][nt + 4] = MFMA16(va[ci][1], r1[nt], acc[ci][nt + 4]);
      }
      produce_tile(buf ^ 1, 1, nt);
    }
    // --- prefetches for later chunks (guarded: OOB otherwise) ---
    if (chunk < 62) loadQ(chunk + 2);
    if (chunk < 63) loadV(chunk + 1);
  }

  float* out_b = out + (size_t)b * 512 * 4096;
#pragma unroll
  for (int ci = 0; ci < 4; ++ci)
#pragma unroll
    for (int nt = 0; nt < 8; ++nt) {
      const int n = nbase + nt * 16 + l15;
      const int c0 = cbase + ci * 16 + quad * 4;
#pragma unroll
      for (int r = 0; r < 4; ++r) out_b[(size_t)(c0 + r) * 4096 + n] = acc[ci][nt][r];
    }
}

// ---------------- launch ----------------
extern "C" void kernel_launch(void* const* d_in, const int* in_sizes, int n_in,
                              void* d_out, int out_size, void* d_ws, size_t ws_size,
                              hipStream_t stream) {
  const float* x  = (const float*)d_in[0];   // [8,512,64,64]
  const float* Wq = (const float*)d_in[1];   // [32,512]
  const float* Wk = (const float*)d_in[2];   // [32,512]
  const float* Wv = (const float*)d_in[3];   // [512,512]
  float* out = (float*)d_out;                // [8,512,64,64]

  char* ws = (char*)d_ws;
  ushort* vb  = (ushort*)(ws + 0);           // 33,554,432 B
  ushort* xT  = (ushort*)(ws + 33554432);    // 33,554,432 B
  ushort* qb  = (ushort*)(ws + 67108864);    //  2,097,152 B
  ushort* kb  = (ushort*)(ws + 69206016);    //  2,097,152 B
  ushort* Wvb = (ushort*)(ws + 71303168);    //    524,288 B
  ushort* Wqb = (ushort*)(ws + 71827456);    //     32,768 B
  ushort* Wkb = (ushort*)(ws + 71860224);    //     32,768 B
  float*  Lrs = (float*)(ws + 71892992);     //    131,072 B  (total 72,024,064)

  hipLaunchKernelGGL(k_cvt_w, dim3(1152), dim3(256), 0, stream, Wq, Wk, Wv, Wqb, Wkb, Wvb);
  hipLaunchKernelGGL(k_xpose, dim3(16, 8, 8), dim3(256), 0, stream, x, xT);
  hipLaunchKernelGGL(k_proj, dim3(64, 8), dim3(256), 0, stream, xT, Wqb, Wkb, Wvb, qb, kb, vb);
  hipLaunchKernelGGL(k_pass1, dim3(64, 8), dim3(256), 0, stream, qb, kb, Lrs);
  hipLaunchKernelGGL(k_pass2, dim3(512), dim3(256), 0, stream, qb, kb, vb, Lrs, out);
}

// Round 3
// 363.335 us; speedup vs baseline: 1.0704x; 1.0704x over previous
//
#include <hip/hip_runtime.h>
#include <hip/hip_bf16.h>

// SelfAttention non-local block: B=8, C=512, N=4096, CQK=32.  All-MFMA bf16 path.
// v6:
//  - k_pass2 restructured: 512-thread blocks spanning all 512 c (grid 256 = 8b x
//    32ntb). v5 had two cb-blocks per (b,ntb) computing the IDENTICAL P tile
//    (QK MFMA + exp2 + pack + LDS write all duplicated 2x per CU). Now P is
//    produced once: per-wave produce work halves (4 tiles), LDS writes halve,
//    redundant 8.6 GF of QK eliminated. Per-wave consume state unchanged
//    (64c x 128n per wave) so the 128-VGPR/128-AGPR budget is preserved.
//  - exp2f -> __builtin_amdgcn_exp2f (bare v_exp_f32) in pass1/pass2: OCML's
//    guarded exp2 is ~7 VALU/call; inputs are S'+Lneg <= 0 (P <= 1) in pass2
//    and |S'| small in pass1 -- native range, sub-(-126) flushes are ~0 terms.
// ws: vb 33.5MB | xT 33.5MB | qb 2MB | kb 2MB | Wvb 512KB | Wqb 32KB | Wkb 32KB | Lneg 128KB

typedef __attribute__((ext_vector_type(8))) short s16x8;
typedef __attribute__((ext_vector_type(4))) float f32x4;

#define MFMA16(a, b, c) __builtin_amdgcn_mfma_f32_16x16x32_bf16((a), (b), (c), 0, 0, 0)

__device__ __forceinline__ ushort f2bf(float f) {
  union { float f; unsigned u; } v; v.f = f;
  return (ushort)((v.u + 0x8000u) >> 16);
}
__device__ __forceinline__ unsigned pack_bf16(float lo, float hi) {  // (hi<<16)|lo
  union { float f; unsigned u; } a, b; a.f = lo; b.f = hi;
  return __builtin_amdgcn_perm(b.u + 0x8000u, a.u + 0x8000u, 0x07060302u);
}
__device__ __forceinline__ float fexp2(float x) { return __builtin_amdgcn_exp2f(x); }

// ---------------- kernel 1: weights -> bf16 (Wq pre-scaled by log2e) ----------------
__global__ void k_cvt_w(const float* __restrict__ Wq, const float* __restrict__ Wk,
                        const float* __restrict__ Wv, ushort* __restrict__ Wqb,
                        ushort* __restrict__ Wkb, ushort* __restrict__ Wvb) {
  int i = blockIdx.x * 256 + threadIdx.x;
  if (i < 262144) Wvb[i] = f2bf(Wv[i]);
  else if (i < 278528) Wqb[i - 262144] = f2bf(Wq[i - 262144] * 1.4426950408889634f);
  else if (i < 294912) Wkb[i - 278528] = f2bf(Wk[i - 278528]);
}

// ---------------- kernel 2: transpose x -> xT bf16 ----------------
// Tile 64c x 256n. Phase1: float4 row loads (1KB contiguous per row), pack n-pairs,
// SoA LDS U[2][64][65] (even/odd pair split => <=2-way banks). Phase2: 8-lane groups
// build 128B-contiguous xT rows via v_perm extraction.
__global__ __launch_bounds__(256) void k_xpose(const float* __restrict__ x,
                                               ushort* __restrict__ xT) {
  const int b = blockIdx.z, c0 = blockIdx.y * 64, n0 = blockIdx.x * 256;
  __shared__ uint U[2][64][65];
  const int t = threadIdx.x;
  const int wv = t >> 6, ln = t & 63;
  const float* xp = x + ((size_t)b * 512 + c0 + wv * 16) * 4096 + n0 + ln * 4;
#pragma unroll
  for (int i = 0; i < 16; ++i) {
    float4 f = *(const float4*)(xp + (size_t)i * 4096);
    U[0][wv * 16 + i][ln] = pack_bf16(f.x, f.y);   // pairs (4ln,4ln+1)   -> pair idx 2ln
    U[1][wv * 16 + i][ln] = pack_bf16(f.z, f.w);   // pairs (4ln+2,4ln+3) -> pair idx 2ln+1
  }
  __syncthreads();
  const int c_seg = (t & 7) * 8;
#pragma unroll
  for (int pass = 0; pass < 8; ++pass) {
    const int nl = pass * 32 + (t >> 3);
    const int p = nl >> 1;              // pair index
    const int h = p & 1, idx = p >> 1;  // SoA half, slot
    const uint sel = (nl & 1) ? 0x07060302u : 0x05040100u;
    uint o[4];
#pragma unroll
    for (int j = 0; j < 4; ++j) {
      uint ua = U[h][c_seg + 2 * j][idx];
      uint ub = U[h][c_seg + 2 * j + 1][idx];
      o[j] = __builtin_amdgcn_perm(ub, ua, sel);   // (bf(c_odd)<<16)|bf(c_even)
    }
    *(uint4*)(xT + ((size_t)b * 4096 + n0 + nl) * 512 + c0 + c_seg) = *(uint4*)o;
  }
}

// ---------------- kernel 3: fused q/k/v projection from xT ----------------
__global__ __launch_bounds__(256, 2) void k_proj(const ushort* __restrict__ xT,
                                                 const ushort* __restrict__ Wqb,
                                                 const ushort* __restrict__ Wkb,
                                                 const ushort* __restrict__ Wvb,
                                                 ushort* __restrict__ qb,
                                                 ushort* __restrict__ kb,
                                                 ushort* __restrict__ vb) {
  const int b = blockIdx.y, n0 = blockIdx.x * 64;
  const int lane = threadIdx.x & 63, w = threadIdx.x >> 6;
  const int quad = lane >> 4, l15 = lane & 15;
  const ushort* xT_b = xT + (size_t)b * 4096 * 512;

  const ushort* Wqk = (w < 2) ? (Wqb + (size_t)(w * 16 + l15) * 512)
                              : (Wkb + (size_t)((w - 2) * 16 + l15) * 512);

  f32x4 accv[8][4], accqk[4];
#pragma unroll
  for (int i = 0; i < 8; ++i)
#pragma unroll
    for (int nt = 0; nt < 4; ++nt) accv[i][nt] = {0.f, 0.f, 0.f, 0.f};
#pragma unroll
  for (int nt = 0; nt < 4; ++nt) accqk[nt] = {0.f, 0.f, 0.f, 0.f};

  for (int k0 = 0; k0 < 512; k0 += 32) {
    s16x8 bx[4];
#pragma unroll
    for (int nt = 0; nt < 4; ++nt)
      bx[nt] = *(const s16x8*)(xT_b + (size_t)(n0 + nt * 16 + l15) * 512 + k0 + quad * 8);
#pragma unroll
    for (int i = 0; i < 8; ++i) {
      s16x8 av = *(const s16x8*)(Wvb + (size_t)((8 * w + i) * 16 + l15) * 512 + k0 + quad * 8);
#pragma unroll
      for (int nt = 0; nt < 4; ++nt) accv[i][nt] = MFMA16(av, bx[nt], accv[i][nt]);
    }
    s16x8 aqk = *(const s16x8*)(Wqk + k0 + quad * 8);
#pragma unroll
    for (int nt = 0; nt < 4; ++nt) accqk[nt] = MFMA16(aqk, bx[nt], accqk[nt]);
  }

  ushort* vb_b = vb + (size_t)b * 512 * 4096;
#pragma unroll
  for (int i = 0; i < 8; ++i)
#pragma unroll
    for (int nt = 0; nt < 4; ++nt)
#pragma unroll
      for (int r = 0; r < 4; ++r)
        vb_b[(size_t)((8 * w + i) * 16 + quad * 4 + r) * 4096 + n0 + nt * 16 + l15] =
            f2bf(accv[i][nt][r]);

  ushort* qk_out = (w < 2) ? (qb + (size_t)b * 4096 * 32) : (kb + (size_t)b * 4096 * 32);
#pragma unroll
  for (int nt = 0; nt < 4; ++nt) {
    ushort4 u;
    u.x = f2bf(accqk[nt][0]); u.y = f2bf(accqk[nt][1]);
    u.z = f2bf(accqk[nt][2]); u.w = f2bf(accqk[nt][3]);
    *(ushort4*)(qk_out + (size_t)(n0 + nt * 16 + l15) * 32 + (w & 1) * 16 + quad * 4) = u;
  }
}

// ---------------- kernel 4: pass1 — Lneg[b][m] = -log2(sum_n 2^(S'[m,n])) ----------------
__global__ __launch_bounds__(256) void k_pass1(const ushort* __restrict__ qb,
                                               const ushort* __restrict__ kb,
                                               float* __restrict__ Lneg) {
  const int b = blockIdx.y, mt = blockIdx.x;
  const int lane = threadIdx.x & 63, w = threadIdx.x >> 6;
  const int quad = lane >> 4, l15 = lane & 15;
  const int m = mt * 64 + w * 16;
  const ushort* qb_b = qb + (size_t)b * 4096 * 32;
  const ushort* kb_b = kb + (size_t)b * 4096 * 32;
  const s16x8 aqf = *(const s16x8*)(qb_b + (size_t)(m + l15) * 32 + quad * 8);
  float ps[4] = {0.f, 0.f, 0.f, 0.f};
  const f32x4 zf = {0.f, 0.f, 0.f, 0.f};
  for (int n0 = 0; n0 < 4096; n0 += 64) {
#pragma unroll
    for (int nt = 0; nt < 4; ++nt) {
      s16x8 bk = *(const s16x8*)(kb_b + (size_t)(n0 + nt * 16 + l15) * 32 + quad * 8);
      f32x4 s = MFMA16(aqf, bk, zf);
#pragma unroll
      for (int r = 0; r < 4; ++r) ps[r] += fexp2(s[r]);
    }
  }
  for (int off = 1; off < 16; off <<= 1)
#pragma unroll
    for (int r = 0; r < 4; ++r) ps[r] += __shfl_xor(ps[r], off, 64);
  if (l15 == 0)
#pragma unroll
    for (int r = 0; r < 4; ++r)
      Lneg[(size_t)b * 4096 + m + quad * 4 + r] = -log2f(ps[r]);
}

// ---------------- kernel 5: pass2 — out = V @ 2^(S' + Lneg) ----------------
// Grid 256 = 8 b (XCD-aligned: blk&7) x 32 ntb. Block 8 waves (512 thr): tile
// 512c x 128n, chunk 64 m. Each wave: consume 64c x 128n (acc[4][8], as v5);
// produce 4 P tiles (M = w>>1, T = (w&1)*4 + i) -- P built exactly once per CU.
__global__ __launch_bounds__(512, 2) void k_pass2(const ushort* __restrict__ qb,
                                                  const ushort* __restrict__ kb,
                                                  const ushort* __restrict__ vb,
                                                  const float* __restrict__ Lneg,
                                                  float* __restrict__ out) {
  const int blk = blockIdx.x;
  const int b = blk & 7, ntb = blk >> 3;
  const int nbase = ntb * 128;
  const int lane = threadIdx.x & 63, w = threadIdx.x >> 6;   // 8 waves
  const int quad = lane >> 4, l15 = lane & 15;
  const int cbase = w * 64;
  const int swz = l15 & 7;
  const int Mw = w >> 1;               // produce m-tile (0..3)
  const int Tb = (w & 1) * 4;          // produce n-tile base (0 or 4)

  __shared__ __align__(16) ushort PT[2][128 * 64];  // 32 KB; 16B-granule XOR swizzle

  const ushort* qb_b = qb + (size_t)b * 4096 * 32;
  const ushort* kb_b = kb + (size_t)b * 4096 * 32;
  const ushort* vb_b = vb + (size_t)b * 512 * 4096;
  const float* L_b = Lneg + (size_t)b * 4096;

  s16x8 kf[4];  // K rows for this wave's 4 produce n-tiles
#pragma unroll
  for (int i = 0; i < 4; ++i)
    kf[i] = *(const s16x8*)(kb_b + (size_t)(nbase + (Tb + i) * 16 + l15) * 32 + quad * 8);

  f32x4 acc[4][8];
#pragma unroll
  for (int ci = 0; ci < 4; ++ci)
#pragma unroll
    for (int nt = 0; nt < 8; ++nt) acc[ci][nt] = {0.f, 0.f, 0.f, 0.f};

  s16x8 aqp;       // prefetched q A-frag for next produce (single m-tile)
  float4 l4p;      // prefetched Lneg
  s16x8 va[4][2];  // prefetched v A-frags for current chunk

  auto loadQ = [&](int chunk) {
    const int m0 = chunk * 64;
    aqp = *(const s16x8*)(qb_b + (size_t)(m0 + Mw * 16 + l15) * 32 + quad * 8);
    l4p = *(const float4*)(L_b + m0 + Mw * 16 + quad * 4);
  };
  auto loadV = [&](int chunk) {
    const int m0 = chunk * 64;
#pragma unroll
    for (int ci = 0; ci < 4; ++ci) {
      const ushort* vrow = vb_b + (size_t)(cbase + ci * 16 + l15) * 4096 + m0;
      va[ci][0] = *(const s16x8*)(vrow + quad * 8);
      va[ci][1] = *(const s16x8*)(vrow + 32 + quad * 8);
    }
  };
  // one produce tile: QK MFMA (Lneg as C-in) -> exp2 -> pack -> ds_write.
  auto produce_tile = [&](int buf, int i) {
    char* Pw = (char*)&PT[buf][0];
    const int T = Tb + i;
    f32x4 cin; cin.x = l4p.x; cin.y = l4p.y; cin.z = l4p.z; cin.w = l4p.w;
    f32x4 s = MFMA16(aqp, kf[i], cin);               // S' + Lneg  (<= ~0)
    uint2 u;
    u.x = pack_bf16(fexp2(s.x), fexp2(s.y));
    u.y = pack_bf16(fexp2(s.z), fexp2(s.w));
    const int row = T * 16 + l15;
    const int gran = (2 * Mw + (quad >> 1)) ^ swz;
    *(uint2*)(Pw + row * 128 + gran * 16 + (quad & 1) * 8) = u;
  };

  loadQ(0);
#pragma unroll
  for (int i = 0; i < 4; ++i) produce_tile(0, i);    // prologue: produce chunk 0
  loadQ(1);
  loadV(0);

  for (int chunk = 0; chunk < 64; ++chunk) {
    const int buf = chunk & 1;
    __syncthreads();
    const char* P = (const char*)&PT[buf][0];
    // --- first-half P reads (issued before any ds_write of this iteration) ---
    s16x8 p0[4], p1[4];
#pragma unroll
    for (int nt = 0; nt < 4; ++nt) {
      const int row = nt * 16 + l15;
      p0[nt] = *(const s16x8*)(P + row * 128 + (quad ^ swz) * 16);
      p1[nt] = *(const s16x8*)(P + row * 128 + ((4 + quad) ^ swz) * 16);
    }
    // --- consume first half; interleave 2 of the 4 produce tiles (into buf^1) ---
    // (chunk 63's produce reuses aqp(63) in-register and writes a never-read
    //  buffer: numerically and memory-safe, keeps the hot body branch-free.)
#pragma unroll
    for (int nt = 0; nt < 4; ++nt) {
#pragma unroll
      for (int ci = 0; ci < 4; ++ci) {
        acc[ci][nt] = MFMA16(va[ci][0], p0[nt], acc[ci][nt]);
        acc[ci][nt] = MFMA16(va[ci][1], p1[nt], acc[ci][nt]);
      }
      if (nt < 2) produce_tile(buf ^ 1, nt);
    }
    // --- second-half P reads ---
    s16x8 r0[4], r1[4];
#pragma unroll
    for (int nt = 0; nt < 4; ++nt) {
      const int row = (nt + 4) * 16 + l15;
      r0[nt] = *(const s16x8*)(P + row * 128 + (quad ^ swz) * 16);
      r1[nt] = *(const s16x8*)(P + row * 128 + ((4 + quad) ^ swz) * 16);
    }
    // --- consume second half; interleave the other 2 produce tiles ---
#pragma unroll
    for (int nt = 0; nt < 4; ++nt) {
#pragma unroll
      for (int ci = 0; ci < 4; ++ci) {
        acc[ci][nt + 4] = MFMA16(va[ci][0], r0[nt], acc[ci][nt + 4]);
        acc[ci][nt + 4] = MFMA16(va[ci][1], r1[nt], acc[ci][nt + 4]);
      }
      if (nt < 2) produce_tile(buf ^ 1, nt + 2);
    }
    // --- prefetches for later chunks (guarded: OOB otherwise) ---
    if (chunk < 62) loadQ(chunk + 2);
    if (chunk < 63) loadV(chunk + 1);
  }

  float* out_b = out + (size_t)b * 512 * 4096;
#pragma unroll
  for (int ci = 0; ci < 4; ++ci)
#pragma unroll
    for (int nt = 0; nt < 8; ++nt) {
      const int n = nbase + nt * 16 + l15;
      const int c0 = cbase + ci * 16 + quad * 4;
#pragma unroll
      for (int r = 0; r < 4; ++r) out_b[(size_t)(c0 + r) * 4096 + n] = acc[ci][nt][r];
    }
}

// ---------------- launch ----------------
extern "C" void kernel_launch(void* const* d_in, const int* in_sizes, int n_in,
                              void* d_out, int out_size, void* d_ws, size_t ws_size,
                              hipStream_t stream) {
  const float* x  = (const float*)d_in[0];   // [8,512,64,64]
  const float* Wq = (const float*)d_in[1];   // [32,512]
  const float* Wk = (const float*)d_in[2];   // [32,512]
  const float* Wv = (const float*)d_in[3];   // [512,512]
  float* out = (float*)d_out;                // [8,512,64,64]

  char* ws = (char*)d_ws;
  ushort* vb  = (ushort*)(ws + 0);           // 33,554,432 B
  ushort* xT  = (ushort*)(ws + 33554432);    // 33,554,432 B
  ushort* qb  = (ushort*)(ws + 67108864);    //  2,097,152 B
  ushort* kb  = (ushort*)(ws + 69206016);    //  2,097,152 B
  ushort* Wvb = (ushort*)(ws + 71303168);    //    524,288 B
  ushort* Wqb = (ushort*)(ws + 71827456);    //     32,768 B
  ushort* Wkb = (ushort*)(ws + 71860224);    //     32,768 B
  float*  Lrs = (float*)(ws + 71892992);     //    131,072 B  (total 72,024,064)

  hipLaunchKernelGGL(k_cvt_w, dim3(1152), dim3(256), 0, stream, Wq, Wk, Wv, Wqb, Wkb, Wvb);
  hipLaunchKernelGGL(k_xpose, dim3(16, 8, 8), dim3(256), 0, stream, x, xT);
  hipLaunchKernelGGL(k_proj, dim3(64, 8), dim3(256), 0, stream, xT, Wqb, Wkb, Wvb, qb, kb, vb);
  hipLaunchKernelGGL(k_pass1, dim3(64, 8), dim3(256), 0, stream, qb, kb, Lrs);
  hipLaunchKernelGGL(k_pass2, dim3(256), dim3(512), 0, stream, qb, kb, vb, Lrs, out);
}